// Round 21
// baseline (94.821 us; speedup 1.0000x reference)
//
#include <hip/hip_runtime.h>
#include <hip/hip_fp16.h>

#define NPTS  8192
#define DDIM  384
#define ROWS  8
#define NBLK  (NPTS / ROWS)       // 1024
#define HCAP  512
#define NTHR  512
#define NC    52
#define NCELL (NC * NC)           // 2704
#define GY0   -5.2005f
#define GHINV 4.99750124937531f   // 1/0.2001

// ws layout (bytes):
//  csS       half2[NPTS*DDIM]  @ 0         12582912   (sorted-order cos/sin, row = 1536 B)
//  xyS       float2[NPTS]      @ 12582912     65536
//  perm      int[NPTS]         @ 12648448     32768
//  cellStart int[NCELL+1]      @ 12681216     12288

__device__ __forceinline__ int cell_of(float a, float b)
{
    int c1 = (int)floorf((a - GY0) * GHINV);
    int c2 = (int)floorf((b - GY0) * GHINV);
    c1 = min(NC - 1, max(0, c1));
    c2 = min(NC - 1, max(0, c2));
    return c1 * NC + c2;
}

__device__ __forceinline__ __half2 u2h(unsigned u)
{
    union { unsigned u; __half2 h; } v; v.u = u; return v.h;
}

// Fused setup: bin + parallel exclusive-scan + scatter (proven R16-R19).
__global__ __launch_bounds__(1024)
void setup_kernel(const float* __restrict__ pts, int* __restrict__ cellStart,
                  int* __restrict__ perm, float2* __restrict__ xyS)
{
    __shared__ int cnt[NCELL];
    __shared__ int wsum[16];
    const int t    = threadIdx.x;
    const int lane = t & 63, wid = t >> 6;

    for (int c = t; c < NCELL; c += 1024) cnt[c] = 0;
    __syncthreads();
    for (int n = t; n < NPTS; n += 1024)
        atomicAdd(&cnt[cell_of(pts[3 * n + 1], pts[3 * n + 2])], 1);
    __syncthreads();

    const int base = t * 3;                 // 1024*3 >= 2704
    int s = 0;
    for (int c = base; c < base + 3 && c < NCELL; ++c) s += cnt[c];

    int v = s;
    #pragma unroll
    for (int off = 1; off < 64; off <<= 1) {
        int u = __shfl_up(v, off, 64);
        if (lane >= off) v += u;
    }
    if (lane == 63) wsum[wid] = v;
    __syncthreads();
    if (wid == 0 && lane < 16) {
        int x = wsum[lane];
        #pragma unroll
        for (int off = 1; off < 16; off <<= 1) {
            int u = __shfl_up(x, off, 64);
            if (lane >= off) x += u;
        }
        wsum[lane] = x;
    }
    __syncthreads();
    int acc = v - s + (wid ? wsum[wid - 1] : 0);   // exclusive prefix

    for (int c = base; c < base + 3 && c < NCELL; ++c) {
        int val = cnt[c];
        cellStart[c] = acc;
        cnt[c] = acc;                       // becomes scatter cursor
        acc += val;
    }
    if (t == 0) cellStart[NCELL] = NPTS;
    __syncthreads();

    for (int n = t; n < NPTS; n += 1024) {
        float a = pts[3 * n + 1];
        float b = pts[3 * n + 2];
        int pos = atomicAdd(&cnt[cell_of(a, b)], 1);
        perm[pos] = n;
        xyS[pos]  = make_float2(a, b);
    }
}

__global__ __launch_bounds__(DDIM)
void cs_kernel(const float* __restrict__ pts, const float* __restrict__ A,
               const int* __restrict__ perm, __half2* __restrict__ csS)
{
    const int r = blockIdx.x;
    const int t = threadIdx.x;
    const int n = perm[r];
    const float p0 = pts[3 * n + 0];
    const float p1 = pts[3 * n + 1];
    const float p2 = pts[3 * n + 2];
    const float pa = fmaf(p2, A[2 * DDIM + t],
                     fmaf(p1, A[DDIM + t], __fmul_rn(p0, A[t])));
    // fast HW sin/cos: error ~1e-6 << fp16 table ulp (5e-4)
    const float s = __sinf(pa);
    const float c = __cosf(pa);
    csS[r * DDIM + t] = __floats2half2_rn(c, s);
}

// Wave-owns-row: 8 waves/block, wave wv handles sorted row r0+wv end-to-end.
// No __syncthreads, no fold phase, no cross-wave LDS traffic.
__global__ __launch_bounds__(NTHR)
void row_kernel(const __half2* __restrict__ csS, const float2* __restrict__ xyS,
                const int* __restrict__ perm, const int* __restrict__ cellStart,
                float* __restrict__ out)
{
    __shared__ int hits[ROWS][HCAP];

    // balance-preserving XCD swizzle: 64 chunks of 16 blocks (128 sorted rows)
    const int bid = blockIdx.x;
    const int xcd = bid & 7, q = bid >> 3;
    const int ch  = q >> 4, w = q & 15;
    const int blk = (((ch << 3) + xcd) << 4) + w;   // bijective on [0,1024)
    const int r0  = blk * ROWS;

    const int t    = threadIdx.x;
    const int wv   = t >> 6;     // wave id 0..7 = row owner
    const int lane = t & 63;
    const int r    = r0 + wv;

    const float2 me  = xyS[r];
    const float  xi  = me.x;
    const float  yi  = me.y;
    const float  sqi = __fadd_rn(__fmul_rn(xi, xi), __fmul_rn(yi, yi));

    // own 3x3 cell window
    int c1 = (int)floorf((xi - GY0) * GHINV);
    int c2 = (int)floorf((yi - GY0) * GHINV);
    c1 = min(NC - 1, max(0, c1));
    c2 = min(NC - 1, max(0, c2));
    const int c1lo = max(0, c1 - 1), c1hi = min(NC - 1, c1 + 1);
    const int c2lo = max(0, c2 - 1), c2hi = min(NC - 1, c2 + 1);

    // scan: exact fp32 J test (bit-identical formula), ballot-compacted
    // append -> hits[wv] stays SORTED (waves sweep ascending indices
    // concurrently -> L1 temporal sharing across the block's 8 rows)
    int cnt = 0;
    for (int cr = c1lo; cr <= c1hi; ++cr) {
        const int qlo = cellStart[cr * NC + c2lo];
        const int qhi = cellStart[cr * NC + c2hi + 1];
        for (int q0 = qlo; q0 < qhi; q0 += 64) {
            const int qq = q0 + lane;
            bool hit = false;
            if (qq < qhi) {
                const float2 pj  = xyS[qq];
                const float  sqj = __fadd_rn(__fmul_rn(pj.x, pj.x),
                                             __fmul_rn(pj.y, pj.y));
                const float  dot = fmaf(yi, pj.y, __fmul_rn(xi, pj.x));
                const float  d2  = __fsub_rn(__fadd_rn(sqi, sqj),
                                             __fmul_rn(2.0f, dot));
                hit = (d2 < 0.04f);
            }
            const unsigned long long msk = __ballot(hit);
            if (hit) {
                const int pos = cnt +
                    __popcll(msk & ((1ull << lane) - 1ull));
                if (pos < HCAP) hits[wv][pos] = qq;
            }
            cnt += __popcll(msk);
        }
    }
    const int m = cnt < HCAP ? cnt : HCAP;

    // gather: lane owns cols 6*lane..6*lane+5 (24 B, stride-24 pattern =
    // proven fastest); 4-row unroll -> 12 independent 8B loads in flight
    const char* base = (const char*)csS;
    const int   b0   = lane * 24;
    const int*  hl   = hits[wv];

    __half2 a0 = u2h(0), a1 = u2h(0), a2 = u2h(0),
            a3 = u2h(0), a4 = u2h(0), a5 = u2h(0);
    int k = 0;
    for (; k + 4 <= m; k += 4) {
        const int j0 = __builtin_amdgcn_readfirstlane(hl[k + 0]);
        const int j1 = __builtin_amdgcn_readfirstlane(hl[k + 1]);
        const int j2 = __builtin_amdgcn_readfirstlane(hl[k + 2]);
        const int j3 = __builtin_amdgcn_readfirstlane(hl[k + 3]);
        const char* rA = base + j0 * 1536 + b0;
        const char* rB = base + j1 * 1536 + b0;
        const char* rC = base + j2 * 1536 + b0;
        const char* rD = base + j3 * 1536 + b0;
        const uint2 wA0 = *(const uint2*)(rA);
        const uint2 wA1 = *(const uint2*)(rA + 8);
        const uint2 wA2 = *(const uint2*)(rA + 16);
        const uint2 wB0 = *(const uint2*)(rB);
        const uint2 wB1 = *(const uint2*)(rB + 8);
        const uint2 wB2 = *(const uint2*)(rB + 16);
        const uint2 wC0 = *(const uint2*)(rC);
        const uint2 wC1 = *(const uint2*)(rC + 8);
        const uint2 wC2 = *(const uint2*)(rC + 16);
        const uint2 wD0 = *(const uint2*)(rD);
        const uint2 wD1 = *(const uint2*)(rD + 8);
        const uint2 wD2 = *(const uint2*)(rD + 16);
        a0 = __hadd2(a0, u2h(wA0.x)); a1 = __hadd2(a1, u2h(wA0.y));
        a2 = __hadd2(a2, u2h(wA1.x)); a3 = __hadd2(a3, u2h(wA1.y));
        a4 = __hadd2(a4, u2h(wA2.x)); a5 = __hadd2(a5, u2h(wA2.y));
        a0 = __hadd2(a0, u2h(wB0.x)); a1 = __hadd2(a1, u2h(wB0.y));
        a2 = __hadd2(a2, u2h(wB1.x)); a3 = __hadd2(a3, u2h(wB1.y));
        a4 = __hadd2(a4, u2h(wB2.x)); a5 = __hadd2(a5, u2h(wB2.y));
        a0 = __hadd2(a0, u2h(wC0.x)); a1 = __hadd2(a1, u2h(wC0.y));
        a2 = __hadd2(a2, u2h(wC1.x)); a3 = __hadd2(a3, u2h(wC1.y));
        a4 = __hadd2(a4, u2h(wC2.x)); a5 = __hadd2(a5, u2h(wC2.y));
        a0 = __hadd2(a0, u2h(wD0.x)); a1 = __hadd2(a1, u2h(wD0.y));
        a2 = __hadd2(a2, u2h(wD1.x)); a3 = __hadd2(a3, u2h(wD1.y));
        a4 = __hadd2(a4, u2h(wD2.x)); a5 = __hadd2(a5, u2h(wD2.y));
    }
    for (; k < m; ++k) {
        const int j = __builtin_amdgcn_readfirstlane(hl[k]);
        const char* rA = base + j * 1536 + b0;
        const uint2 wA0 = *(const uint2*)(rA);
        const uint2 wA1 = *(const uint2*)(rA + 8);
        const uint2 wA2 = *(const uint2*)(rA + 16);
        a0 = __hadd2(a0, u2h(wA0.x)); a1 = __hadd2(a1, u2h(wA0.y));
        a2 = __hadd2(a2, u2h(wA1.x)); a3 = __hadd2(a3, u2h(wA1.y));
        a4 = __hadd2(a4, u2h(wA2.x)); a5 = __hadd2(a5, u2h(wA2.y));
    }

    // wave-local norm: lane sums |G_c|^2 over its 6 cols, shfl-reduce 64 lanes
    const float2 f0 = __half22float2(a0), f1 = __half22float2(a1);
    const float2 f2 = __half22float2(a2), f3 = __half22float2(a3);
    const float2 f4 = __half22float2(a4), f5 = __half22float2(a5);
    float p = fmaf(f0.x, f0.x, f0.y * f0.y) + fmaf(f1.x, f1.x, f1.y * f1.y)
            + fmaf(f2.x, f2.x, f2.y * f2.y) + fmaf(f3.x, f3.x, f3.y * f3.y)
            + fmaf(f4.x, f4.x, f4.y * f4.y) + fmaf(f5.x, f5.x, f5.y * f5.y);
    #pragma unroll
    for (int off = 32; off > 0; off >>= 1) p += __shfl_down(p, off, 64);
    const float tot   = __shfl(p, 0, 64);
    const float scale = 19.59591794226543f / sqrtf(tot);   // sqrt(384)/nrm

    // rotate by conj(e^{i pa_i}) using the (hot) table row; write own 6 cols
    const char* rowi = base + r * 1536 + b0;
    const uint2 wi0 = *(const uint2*)(rowi);
    const uint2 wi1 = *(const uint2*)(rowi + 8);
    const uint2 wi2 = *(const uint2*)(rowi + 16);
    const float2 e0 = __half22float2(u2h(wi0.x));
    const float2 e1 = __half22float2(u2h(wi0.y));
    const float2 e2 = __half22float2(u2h(wi1.x));
    const float2 e3 = __half22float2(u2h(wi1.y));
    const float2 e4 = __half22float2(u2h(wi2.x));
    const float2 e5 = __half22float2(u2h(wi2.y));

    float* op = out + perm[r] * DDIM + lane * 6;
    const float g0 = fmaf(f0.x, e0.x, f0.y * e0.y) * scale;
    const float g1 = fmaf(f1.x, e1.x, f1.y * e1.y) * scale;
    const float g2 = fmaf(f2.x, e2.x, f2.y * e2.y) * scale;
    const float g3 = fmaf(f3.x, e3.x, f3.y * e3.y) * scale;
    const float g4 = fmaf(f4.x, e4.x, f4.y * e4.y) * scale;
    const float g5 = fmaf(f5.x, e5.x, f5.y * e5.y) * scale;
    *(float2*)(op + 0) = make_float2(g0, g1);
    *(float2*)(op + 2) = make_float2(g2, g3);
    *(float2*)(op + 4) = make_float2(g4, g5);
}

extern "C" void kernel_launch(void* const* d_in, const int* in_sizes, int n_in,
                              void* d_out, int out_size, void* d_ws, size_t ws_size,
                              hipStream_t stream)
{
    const float* pts = (const float*)d_in[0];
    const float* A   = (const float*)d_in[1];
    if (n_in >= 2 && in_sizes[0] == 3 * DDIM && in_sizes[1] == NPTS * 3) {
        pts = (const float*)d_in[1];
        A   = (const float*)d_in[0];
    }
    char* ws = (char*)d_ws;
    __half2* csS       = (__half2*)(ws + 0);
    float2*  xyS       = (float2*)(ws + 12582912);
    int*     perm      = (int*)(ws + 12648448);
    int*     cellStart = (int*)(ws + 12681216);
    float*   out       = (float*)d_out;

    setup_kernel<<<1, 1024, 0, stream>>>(pts, cellStart, perm, xyS);
    cs_kernel<<<NPTS, DDIM, 0, stream>>>(pts, A, perm, csS);
    row_kernel<<<NBLK, NTHR, 0, stream>>>(csS, xyS, perm, cellStart, out);
}

// Round 22
// 72.460 us; speedup vs baseline: 1.3086x; 1.3086x over previous
//
#include <hip/hip_runtime.h>
#include <hip/hip_fp16.h>

#define NPTS  8192
#define DDIM  384
#define ROWS  8
#define NBLK  (NPTS / ROWS)       // 1024
#define UCAP  1536
#define NTHR  512
#define NSLOT 8
#define NC    52
#define NCELL (NC * NC)           // 2704
#define GY0   -5.2005f
#define GHINV 4.99750124937531f   // 1/0.2001

// ws layout (bytes):
//  csS       half2[NPTS*DDIM]  @ 0         12582912   (sorted-order cos/sin, row = 1536 B)
//  xyS       float2[NPTS]      @ 12582912     65536
//  perm      int[NPTS]         @ 12648448     32768
//  cellStart int[NCELL+1]      @ 12681216     12288
//  cellCnt   int[NCELL]        @ 12693504     12288
//  cellCur   int[NCELL]        @ 12705792     12288

__device__ __forceinline__ int cell_of(float a, float b)
{
    int c1 = (int)floorf((a - GY0) * GHINV);
    int c2 = (int)floorf((b - GY0) * GHINV);
    c1 = min(NC - 1, max(0, c1));
    c2 = min(NC - 1, max(0, c2));
    return c1 * NC + c2;
}

__device__ __forceinline__ __half2 u2h(unsigned u)
{
    union { unsigned u; __half2 h; } v; v.u = u; return v.h;
}
__device__ __forceinline__ unsigned h2u(__half2 h)
{
    union { unsigned u; __half2 h; } v; v.h = h; return v.u;
}

// --- parallel setup: bin -> prefix(parallel scan) -> scatter ---

__global__ void bin_kernel(const float* __restrict__ pts, int* __restrict__ cellCnt)
{
    const int n = blockIdx.x * 256 + threadIdx.x;
    if (n < NPTS)
        atomicAdd(&cellCnt[cell_of(pts[3 * n + 1], pts[3 * n + 2])], 1);
}

__global__ __launch_bounds__(1024)
void prefix_kernel(const int* __restrict__ cellCnt,
                   int* __restrict__ cellStart, int* __restrict__ cellCur)
{
    __shared__ int wsum[16];
    const int t    = threadIdx.x;
    const int lane = t & 63, wid = t >> 6;

    const int base = t * 3;                 // 1024*3 >= 2704
    int c0v = 0, c1v = 0, c2v = 0;
    if (base     < NCELL) c0v = cellCnt[base];
    if (base + 1 < NCELL) c1v = cellCnt[base + 1];
    if (base + 2 < NCELL) c2v = cellCnt[base + 2];
    const int s = c0v + c1v + c2v;

    int v = s;
    #pragma unroll
    for (int off = 1; off < 64; off <<= 1) {
        int u = __shfl_up(v, off, 64);
        if (lane >= off) v += u;
    }
    if (lane == 63) wsum[wid] = v;
    __syncthreads();
    if (wid == 0 && lane < 16) {
        int x = wsum[lane];
        #pragma unroll
        for (int off = 1; off < 16; off <<= 1) {
            int u = __shfl_up(x, off, 64);
            if (lane >= off) x += u;
        }
        wsum[lane] = x;
    }
    __syncthreads();
    int acc = v - s + (wid ? wsum[wid - 1] : 0);   // exclusive prefix

    if (base < NCELL)     { cellStart[base]     = acc; cellCur[base]     = acc; acc += c0v; }
    if (base + 1 < NCELL) { cellStart[base + 1] = acc; cellCur[base + 1] = acc; acc += c1v; }
    if (base + 2 < NCELL) { cellStart[base + 2] = acc; cellCur[base + 2] = acc; }
    if (t == 0) cellStart[NCELL] = NPTS;
}

__global__ void scatter_kernel(const float* __restrict__ pts,
                               int* __restrict__ cellCur,
                               int* __restrict__ perm, float2* __restrict__ xyS)
{
    const int n = blockIdx.x * 256 + threadIdx.x;
    if (n < NPTS) {
        const float a = pts[3 * n + 1];
        const float b = pts[3 * n + 2];
        const int pos = atomicAdd(&cellCur[cell_of(a, b)], 1);
        perm[pos] = n;
        xyS[pos]  = make_float2(a, b);
    }
}

__global__ __launch_bounds__(DDIM)
void cs_kernel(const float* __restrict__ pts, const float* __restrict__ A,
               const int* __restrict__ perm, __half2* __restrict__ csS)
{
    const int r = blockIdx.x;
    const int t = threadIdx.x;
    const int n = perm[r];
    const float p0 = pts[3 * n + 0];
    const float p1 = pts[3 * n + 1];
    const float p2 = pts[3 * n + 2];
    const float pa = fmaf(p2, A[2 * DDIM + t],
                     fmaf(p1, A[DDIM + t], __fmul_rn(p0, A[t])));
    // fast HW sin/cos: error ~1e-6 << fp16 table ulp (5e-4)
    const float s = __sinf(pa);
    const float c = __cosf(pa);
    csS[r * DDIM + t] = __floats2half2_rn(c, s);
}

__global__ __launch_bounds__(NTHR)
void row_kernel(const __half2* __restrict__ csS, const float2* __restrict__ xyS,
                const int* __restrict__ perm, const int* __restrict__ cellStart,
                float* __restrict__ out)
{
    __shared__ int   ulist[UCAP];
    __shared__ int   ucnt;
    __shared__ uint2 partl[NSLOT][64][3];
    __shared__ float red[NSLOT];

    // balance-preserving XCD swizzle: 64 chunks of 16 blocks (128 sorted rows)
    const int bid = blockIdx.x;
    const int xcd = bid & 7, q = bid >> 3;
    const int ch  = q >> 4, w = q & 15;
    const int blk = (((ch << 3) + xcd) << 4) + w;   // bijective on [0,1024)
    const int r0  = blk * ROWS;

    const int t  = threadIdx.x;
    const int ks = t >> 6;      // wave id 0..7  (wave-uniform)
    const int cg = t & 63;      // lane: owns cols 6cg..6cg+5

    if (t == 0) ucnt = 0;
    __syncthreads();

    float rx[ROWS], ry[ROWS], rs[ROWS];
    #pragma unroll
    for (int rr = 0; rr < ROWS; ++rr) {
        const float2 p = xyS[r0 + rr];
        rx[rr] = p.x; ry[rr] = p.y;
        rs[rr] = __fadd_rn(__fmul_rn(p.x, p.x), __fmul_rn(p.y, p.y));
    }

    // dilated cell window over the 8 rows
    int c1lo = NC - 1, c1hi = 0, c2lo = NC - 1, c2hi = 0;
    #pragma unroll
    for (int rr = 0; rr < ROWS; ++rr) {
        int c1 = (int)floorf((rx[rr] - GY0) * GHINV);
        int c2 = (int)floorf((ry[rr] - GY0) * GHINV);
        c1 = min(NC - 1, max(0, c1)); c2 = min(NC - 1, max(0, c2));
        c1lo = min(c1lo, c1); c1hi = max(c1hi, c1);
        c2lo = min(c2lo, c2); c2hi = max(c2hi, c2);
    }
    c1lo = max(0, c1lo - 1); c1hi = min(NC - 1, c1hi + 1);
    c2lo = max(0, c2lo - 1); c2hi = min(NC - 1, c2hi + 1);

    // scan: exact fp32 J test (bit-identical) vs the 8 rows -> 8-bit mask;
    // ballot-compacted append: ONE ucnt atomic per wave-iteration
    for (int cr = c1lo; cr <= c1hi; ++cr) {
        const int qlo = cellStart[cr * NC + c2lo];
        const int qhi = cellStart[cr * NC + c2hi + 1];
        for (int q0 = qlo + ks * 64; q0 < qhi; q0 += NTHR) {
            const int qq = q0 + cg;
            int bits = 0;
            if (qq < qhi) {
                const float2 pj  = xyS[qq];
                const float  sqj = __fadd_rn(__fmul_rn(pj.x, pj.x),
                                             __fmul_rn(pj.y, pj.y));
                #pragma unroll
                for (int rr = 0; rr < ROWS; ++rr) {
                    const float dot = fmaf(ry[rr], pj.y, __fmul_rn(rx[rr], pj.x));
                    const float d2  = __fsub_rn(__fadd_rn(rs[rr], sqj),
                                                __fmul_rn(2.0f, dot));
                    if (d2 < 0.04f) bits |= (1 << rr);
                }
            }
            const unsigned long long msk = __ballot(bits != 0);
            int wbase = 0;
            const int wcnt = __popcll(msk);
            if (cg == 0 && wcnt) wbase = atomicAdd(&ucnt, wcnt);
            wbase = __shfl(wbase, 0, 64);
            if (bits) {
                const int pos = wbase +
                    __popcll(msk & ((1ull << cg) - 1ull));
                if (pos < UCAP) ulist[pos] = qq | (bits << 13);
            }
        }
    }
    __syncthreads();
    const int U = ucnt < UCAP ? ucnt : UCAP;

    // gather: slot ks takes union entries k+ks (k step 8); per entry 3 loads
    // (stride-24, proven fastest) + wave-uniform mask branches into 8 per-row
    // fp16 accumulator sets
    const char* base = (const char*)csS;
    const int   b0   = cg * 24;

    __half2 acc[ROWS][6];
    #pragma unroll
    for (int rr = 0; rr < ROWS; ++rr)
        #pragma unroll
        for (int c = 0; c < 6; ++c) acc[rr][c] = u2h(0);

    int k = 0;
    for (; k + 16 <= U; k += 16) {
        const int pkA = __builtin_amdgcn_readfirstlane(ulist[k + ks]);
        const int pkB = __builtin_amdgcn_readfirstlane(ulist[k + 8 + ks]);
        const int jA = pkA & 0x1FFF, mA = pkA >> 13;
        const int jB = pkB & 0x1FFF, mB = pkB >> 13;
        const char* rA = base + jA * 1536 + b0;
        const char* rB = base + jB * 1536 + b0;
        const uint2 wA0 = *(const uint2*)(rA);
        const uint2 wA1 = *(const uint2*)(rA + 8);
        const uint2 wA2 = *(const uint2*)(rA + 16);
        const uint2 wB0 = *(const uint2*)(rB);
        const uint2 wB1 = *(const uint2*)(rB + 8);
        const uint2 wB2 = *(const uint2*)(rB + 16);
        #pragma unroll
        for (int rr = 0; rr < ROWS; ++rr) {
            if (mA & (1 << rr)) {
                acc[rr][0] = __hadd2(acc[rr][0], u2h(wA0.x));
                acc[rr][1] = __hadd2(acc[rr][1], u2h(wA0.y));
                acc[rr][2] = __hadd2(acc[rr][2], u2h(wA1.x));
                acc[rr][3] = __hadd2(acc[rr][3], u2h(wA1.y));
                acc[rr][4] = __hadd2(acc[rr][4], u2h(wA2.x));
                acc[rr][5] = __hadd2(acc[rr][5], u2h(wA2.y));
            }
        }
        #pragma unroll
        for (int rr = 0; rr < ROWS; ++rr) {
            if (mB & (1 << rr)) {
                acc[rr][0] = __hadd2(acc[rr][0], u2h(wB0.x));
                acc[rr][1] = __hadd2(acc[rr][1], u2h(wB0.y));
                acc[rr][2] = __hadd2(acc[rr][2], u2h(wB1.x));
                acc[rr][3] = __hadd2(acc[rr][3], u2h(wB1.y));
                acc[rr][4] = __hadd2(acc[rr][4], u2h(wB2.x));
                acc[rr][5] = __hadd2(acc[rr][5], u2h(wB2.y));
            }
        }
    }
    for (; k < U; k += NSLOT) {
        if (k + ks < U) {                            // wave-uniform
            const int pkA = __builtin_amdgcn_readfirstlane(ulist[k + ks]);
            const int jA = pkA & 0x1FFF, mA = pkA >> 13;
            const char* rA = base + jA * 1536 + b0;
            const uint2 wA0 = *(const uint2*)(rA);
            const uint2 wA1 = *(const uint2*)(rA + 8);
            const uint2 wA2 = *(const uint2*)(rA + 16);
            #pragma unroll
            for (int rr = 0; rr < ROWS; ++rr) {
                if (mA & (1 << rr)) {
                    acc[rr][0] = __hadd2(acc[rr][0], u2h(wA0.x));
                    acc[rr][1] = __hadd2(acc[rr][1], u2h(wA0.y));
                    acc[rr][2] = __hadd2(acc[rr][2], u2h(wA1.x));
                    acc[rr][3] = __hadd2(acc[rr][3], u2h(wA1.y));
                    acc[rr][4] = __hadd2(acc[rr][4], u2h(wA2.x));
                    acc[rr][5] = __hadd2(acc[rr][5], u2h(wA2.y));
                }
            }
        }
    }

    // fold + norm + write, one row at a time through the shared partl buffer
    for (int rr = 0; rr < ROWS; ++rr) {
        partl[ks][cg][0] = make_uint2(h2u(acc[rr][0]), h2u(acc[rr][1]));
        partl[ks][cg][1] = make_uint2(h2u(acc[rr][2]), h2u(acc[rr][3]));
        partl[ks][cg][2] = make_uint2(h2u(acc[rr][4]), h2u(acc[rr][5]));
        __syncthreads();

        float re = 0.f, im = 0.f;
        if (t < DDIM) {
            const int sc = t / 6, comp = t % 6;
            #pragma unroll
            for (int s = 0; s < NSLOT; ++s) {
                const uint2 ww = partl[s][sc][comp >> 1];
                const float2 f = __half22float2(u2h((comp & 1) ? ww.y : ww.x));
                re += f.x; im += f.y;
            }
        }

        float p = fmaf(re, re, im * im);
        #pragma unroll
        for (int off = 32; off > 0; off >>= 1) p += __shfl_down(p, off, 64);
        if ((t & 63) == 0) red[t >> 6] = p;
        __syncthreads();
        const float tot = ((red[0] + red[1]) + (red[2] + red[3]))
                        + ((red[4] + red[5]) + (red[6] + red[7]));
        const float scale = 19.59591794226543f / sqrtf(tot);   // sqrt(384)/nrm

        if (t < DDIM) {
            const float2 ci = __half22float2(csS[(r0 + rr) * DDIM + t]);
            const float  Gr = fmaf(re, ci.x, im * ci.y);
            out[perm[r0 + rr] * DDIM + t] = Gr * scale;
        }
        __syncthreads();   // protect partl/red before next row's overwrite
    }
}

extern "C" void kernel_launch(void* const* d_in, const int* in_sizes, int n_in,
                              void* d_out, int out_size, void* d_ws, size_t ws_size,
                              hipStream_t stream)
{
    const float* pts = (const float*)d_in[0];
    const float* A   = (const float*)d_in[1];
    if (n_in >= 2 && in_sizes[0] == 3 * DDIM && in_sizes[1] == NPTS * 3) {
        pts = (const float*)d_in[1];
        A   = (const float*)d_in[0];
    }
    char* ws = (char*)d_ws;
    __half2* csS       = (__half2*)(ws + 0);
    float2*  xyS       = (float2*)(ws + 12582912);
    int*     perm      = (int*)(ws + 12648448);
    int*     cellStart = (int*)(ws + 12681216);
    int*     cellCnt   = (int*)(ws + 12693504);
    int*     cellCur   = (int*)(ws + 12705792);
    float*   out       = (float*)d_out;

    hipMemsetAsync(cellCnt, 0, NCELL * sizeof(int), stream);
    bin_kernel<<<NPTS / 256, 256, 0, stream>>>(pts, cellCnt);
    prefix_kernel<<<1, 1024, 0, stream>>>(cellCnt, cellStart, cellCur);
    scatter_kernel<<<NPTS / 256, 256, 0, stream>>>(pts, cellCur, perm, xyS);
    cs_kernel<<<NPTS, DDIM, 0, stream>>>(pts, A, perm, csS);
    row_kernel<<<NBLK, NTHR, 0, stream>>>(csS, xyS, perm, cellStart, out);
}

// Round 23
// 66.255 us; speedup vs baseline: 1.4311x; 1.0936x over previous
//
#include <hip/hip_runtime.h>
#include <hip/hip_fp16.h>

#define NPTS  8192
#define DDIM  384
#define ROWS  8
#define NBLK  (NPTS / ROWS)       // 1024
#define UCAP  1536
#define NTHR  512
#define NSLOT 8
#define NC    52
#define NCELL (NC * NC)           // 2704
#define GY0   -5.2005f
#define GHINV 4.99750124937531f   // 1/0.2001

// ws layout (bytes):
//  csS       half2[NPTS*DDIM]  @ 0         12582912   (sorted-order cos/sin, row = 1536 B)
//  xyS       float2[NPTS]      @ 12582912     65536
//  perm      int[NPTS]         @ 12648448     32768
//  cellStart int[NCELL+1]      @ 12681216     12288

__device__ __forceinline__ int cell_of(float a, float b)
{
    int c1 = (int)floorf((a - GY0) * GHINV);
    int c2 = (int)floorf((b - GY0) * GHINV);
    c1 = min(NC - 1, max(0, c1));
    c2 = min(NC - 1, max(0, c2));
    return c1 * NC + c2;
}

__device__ __forceinline__ __half2 u2h(unsigned u)
{
    union { unsigned u; __half2 h; } v; v.u = u; return v.h;
}
__device__ __forceinline__ unsigned h2u(__half2 h)
{
    union { unsigned u; __half2 h; } v; v.h = h; return v.u;
}

// Fused setup: bin + parallel exclusive-scan + scatter, one workgroup
// (R19-proven; best total came with this version).
__global__ __launch_bounds__(1024)
void setup_kernel(const float* __restrict__ pts, int* __restrict__ cellStart,
                  int* __restrict__ perm, float2* __restrict__ xyS)
{
    __shared__ int cnt[NCELL];
    __shared__ int wsum[16];
    const int t    = threadIdx.x;
    const int lane = t & 63, wid = t >> 6;

    for (int c = t; c < NCELL; c += 1024) cnt[c] = 0;
    __syncthreads();
    for (int n = t; n < NPTS; n += 1024)
        atomicAdd(&cnt[cell_of(pts[3 * n + 1], pts[3 * n + 2])], 1);
    __syncthreads();

    const int base = t * 3;                 // 1024*3 >= 2704
    int s = 0;
    for (int c = base; c < base + 3 && c < NCELL; ++c) s += cnt[c];

    int v = s;
    #pragma unroll
    for (int off = 1; off < 64; off <<= 1) {
        int u = __shfl_up(v, off, 64);
        if (lane >= off) v += u;
    }
    if (lane == 63) wsum[wid] = v;
    __syncthreads();
    if (wid == 0 && lane < 16) {
        int x = wsum[lane];
        #pragma unroll
        for (int off = 1; off < 16; off <<= 1) {
            int u = __shfl_up(x, off, 64);
            if (lane >= off) x += u;
        }
        wsum[lane] = x;
    }
    __syncthreads();
    int acc = v - s + (wid ? wsum[wid - 1] : 0);   // exclusive prefix

    for (int c = base; c < base + 3 && c < NCELL; ++c) {
        int val = cnt[c];
        cellStart[c] = acc;
        cnt[c] = acc;                       // becomes scatter cursor
        acc += val;
    }
    if (t == 0) cellStart[NCELL] = NPTS;
    __syncthreads();

    for (int n = t; n < NPTS; n += 1024) {
        float a = pts[3 * n + 1];
        float b = pts[3 * n + 2];
        int pos = atomicAdd(&cnt[cell_of(a, b)], 1);
        perm[pos] = n;
        xyS[pos]  = make_float2(a, b);
    }
}

// Fat cs: 1024 blocks x 384 threads, 8 rows/block; A loaded once per thread.
__global__ __launch_bounds__(DDIM)
void cs_kernel(const float* __restrict__ pts, const float* __restrict__ A,
               const int* __restrict__ perm, __half2* __restrict__ csS)
{
    const int t  = threadIdx.x;
    const int r0 = blockIdx.x * 8;
    const float a0 = A[t];
    const float a1 = A[DDIM + t];
    const float a2 = A[2 * DDIM + t];
    #pragma unroll
    for (int i = 0; i < 8; ++i) {
        const int r = r0 + i;
        const int n = perm[r];
        const float p0 = pts[3 * n + 0];
        const float p1 = pts[3 * n + 1];
        const float p2 = pts[3 * n + 2];
        const float pa = fmaf(p2, a2, fmaf(p1, a1, __fmul_rn(p0, a0)));
        // fast HW sin/cos: error ~1e-6 << fp16 table ulp (5e-4)
        csS[r * DDIM + t] = __floats2half2_rn(__cosf(pa), __sinf(pa));
    }
}

__global__ __launch_bounds__(NTHR)
void row_kernel(const __half2* __restrict__ csS, const float2* __restrict__ xyS,
                const int* __restrict__ perm, const int* __restrict__ cellStart,
                float* __restrict__ out)
{
    __shared__ int   ulist[UCAP];
    __shared__ int   ucnt;
    __shared__ uint2 partl[NSLOT][64][6];   // 2 rows per fold pass
    __shared__ float red[2][NSLOT];

    // balance-preserving XCD swizzle: 64 chunks of 16 blocks (128 sorted rows)
    const int bid = blockIdx.x;
    const int xcd = bid & 7, q = bid >> 3;
    const int ch  = q >> 4, w = q & 15;
    const int blk = (((ch << 3) + xcd) << 4) + w;   // bijective on [0,1024)
    const int r0  = blk * ROWS;

    const int t  = threadIdx.x;
    const int ks = t >> 6;      // wave id 0..7  (wave-uniform)
    const int cg = t & 63;      // lane: owns cols 6cg..6cg+5

    if (t == 0) ucnt = 0;
    __syncthreads();

    float rx[ROWS], ry[ROWS], rs[ROWS];
    #pragma unroll
    for (int rr = 0; rr < ROWS; ++rr) {
        const float2 p = xyS[r0 + rr];
        rx[rr] = p.x; ry[rr] = p.y;
        rs[rr] = __fadd_rn(__fmul_rn(p.x, p.x), __fmul_rn(p.y, p.y));
    }

    // dilated cell window over the 8 rows
    int c1lo = NC - 1, c1hi = 0, c2lo = NC - 1, c2hi = 0;
    #pragma unroll
    for (int rr = 0; rr < ROWS; ++rr) {
        int c1 = (int)floorf((rx[rr] - GY0) * GHINV);
        int c2 = (int)floorf((ry[rr] - GY0) * GHINV);
        c1 = min(NC - 1, max(0, c1)); c2 = min(NC - 1, max(0, c2));
        c1lo = min(c1lo, c1); c1hi = max(c1hi, c1);
        c2lo = min(c2lo, c2); c2hi = max(c2hi, c2);
    }
    c1lo = max(0, c1lo - 1); c1hi = min(NC - 1, c1hi + 1);
    c2lo = max(0, c2lo - 1); c2hi = min(NC - 1, c2hi + 1);

    // scan: exact fp32 J test (bit-identical) vs the 8 rows -> 8-bit mask;
    // ballot-compacted append: ONE ucnt atomic per wave-iteration
    for (int cr = c1lo; cr <= c1hi; ++cr) {
        const int qlo = cellStart[cr * NC + c2lo];
        const int qhi = cellStart[cr * NC + c2hi + 1];
        for (int q0 = qlo + ks * 64; q0 < qhi; q0 += NTHR) {
            const int qq = q0 + cg;
            int bits = 0;
            if (qq < qhi) {
                const float2 pj  = xyS[qq];
                const float  sqj = __fadd_rn(__fmul_rn(pj.x, pj.x),
                                             __fmul_rn(pj.y, pj.y));
                #pragma unroll
                for (int rr = 0; rr < ROWS; ++rr) {
                    const float dot = fmaf(ry[rr], pj.y, __fmul_rn(rx[rr], pj.x));
                    const float d2  = __fsub_rn(__fadd_rn(rs[rr], sqj),
                                                __fmul_rn(2.0f, dot));
                    if (d2 < 0.04f) bits |= (1 << rr);
                }
            }
            const unsigned long long msk = __ballot(bits != 0);
            int wbase = 0;
            const int wcnt = __popcll(msk);
            if (cg == 0 && wcnt) wbase = atomicAdd(&ucnt, wcnt);
            wbase = __shfl(wbase, 0, 64);
            if (bits) {
                const int pos = wbase +
                    __popcll(msk & ((1ull << cg) - 1ull));
                if (pos < UCAP) ulist[pos] = qq | (bits << 13);
            }
        }
    }
    __syncthreads();
    const int U = ucnt < UCAP ? ucnt : UCAP;

    // gather: slot ks takes union entries k+ks (k step 8); per entry 3 loads
    // (stride-24, proven fastest) + wave-uniform mask branches into 8 per-row
    // fp16 accumulator sets
    const char* base = (const char*)csS;
    const int   b0   = cg * 24;

    __half2 acc[ROWS][6];
    #pragma unroll
    for (int rr = 0; rr < ROWS; ++rr)
        #pragma unroll
        for (int c = 0; c < 6; ++c) acc[rr][c] = u2h(0);

    int k = 0;
    for (; k + 16 <= U; k += 16) {
        const int pkA = __builtin_amdgcn_readfirstlane(ulist[k + ks]);
        const int pkB = __builtin_amdgcn_readfirstlane(ulist[k + 8 + ks]);
        const int jA = pkA & 0x1FFF, mA = pkA >> 13;
        const int jB = pkB & 0x1FFF, mB = pkB >> 13;
        const char* rA = base + jA * 1536 + b0;
        const char* rB = base + jB * 1536 + b0;
        const uint2 wA0 = *(const uint2*)(rA);
        const uint2 wA1 = *(const uint2*)(rA + 8);
        const uint2 wA2 = *(const uint2*)(rA + 16);
        const uint2 wB0 = *(const uint2*)(rB);
        const uint2 wB1 = *(const uint2*)(rB + 8);
        const uint2 wB2 = *(const uint2*)(rB + 16);
        #pragma unroll
        for (int rr = 0; rr < ROWS; ++rr) {
            if (mA & (1 << rr)) {
                acc[rr][0] = __hadd2(acc[rr][0], u2h(wA0.x));
                acc[rr][1] = __hadd2(acc[rr][1], u2h(wA0.y));
                acc[rr][2] = __hadd2(acc[rr][2], u2h(wA1.x));
                acc[rr][3] = __hadd2(acc[rr][3], u2h(wA1.y));
                acc[rr][4] = __hadd2(acc[rr][4], u2h(wA2.x));
                acc[rr][5] = __hadd2(acc[rr][5], u2h(wA2.y));
            }
        }
        #pragma unroll
        for (int rr = 0; rr < ROWS; ++rr) {
            if (mB & (1 << rr)) {
                acc[rr][0] = __hadd2(acc[rr][0], u2h(wB0.x));
                acc[rr][1] = __hadd2(acc[rr][1], u2h(wB0.y));
                acc[rr][2] = __hadd2(acc[rr][2], u2h(wB1.x));
                acc[rr][3] = __hadd2(acc[rr][3], u2h(wB1.y));
                acc[rr][4] = __hadd2(acc[rr][4], u2h(wB2.x));
                acc[rr][5] = __hadd2(acc[rr][5], u2h(wB2.y));
            }
        }
    }
    for (; k < U; k += NSLOT) {
        if (k + ks < U) {                            // wave-uniform
            const int pkA = __builtin_amdgcn_readfirstlane(ulist[k + ks]);
            const int jA = pkA & 0x1FFF, mA = pkA >> 13;
            const char* rA = base + jA * 1536 + b0;
            const uint2 wA0 = *(const uint2*)(rA);
            const uint2 wA1 = *(const uint2*)(rA + 8);
            const uint2 wA2 = *(const uint2*)(rA + 16);
            #pragma unroll
            for (int rr = 0; rr < ROWS; ++rr) {
                if (mA & (1 << rr)) {
                    acc[rr][0] = __hadd2(acc[rr][0], u2h(wA0.x));
                    acc[rr][1] = __hadd2(acc[rr][1], u2h(wA0.y));
                    acc[rr][2] = __hadd2(acc[rr][2], u2h(wA1.x));
                    acc[rr][3] = __hadd2(acc[rr][3], u2h(wA1.y));
                    acc[rr][4] = __hadd2(acc[rr][4], u2h(wA2.x));
                    acc[rr][5] = __hadd2(acc[rr][5], u2h(wA2.y));
                }
            }
        }
    }

    // fold + norm + write, TWO rows per pass (8 barriers instead of 16)
    for (int rr = 0; rr < ROWS; rr += 2) {
        partl[ks][cg][0] = make_uint2(h2u(acc[rr][0]),     h2u(acc[rr][1]));
        partl[ks][cg][1] = make_uint2(h2u(acc[rr][2]),     h2u(acc[rr][3]));
        partl[ks][cg][2] = make_uint2(h2u(acc[rr][4]),     h2u(acc[rr][5]));
        partl[ks][cg][3] = make_uint2(h2u(acc[rr + 1][0]), h2u(acc[rr + 1][1]));
        partl[ks][cg][4] = make_uint2(h2u(acc[rr + 1][2]), h2u(acc[rr + 1][3]));
        partl[ks][cg][5] = make_uint2(h2u(acc[rr + 1][4]), h2u(acc[rr + 1][5]));
        __syncthreads();

        float reA = 0.f, imA = 0.f, reB = 0.f, imB = 0.f;
        if (t < DDIM) {
            const int sc = t / 6, comp = t % 6;
            #pragma unroll
            for (int s = 0; s < NSLOT; ++s) {
                const uint2 wwA = partl[s][sc][comp >> 1];
                const uint2 wwB = partl[s][sc][3 + (comp >> 1)];
                const float2 fA = __half22float2(u2h((comp & 1) ? wwA.y : wwA.x));
                const float2 fB = __half22float2(u2h((comp & 1) ? wwB.y : wwB.x));
                reA += fA.x; imA += fA.y;
                reB += fB.x; imB += fB.y;
            }
        }

        float pA = fmaf(reA, reA, imA * imA);
        float pB = fmaf(reB, reB, imB * imB);
        #pragma unroll
        for (int off = 32; off > 0; off >>= 1) {
            pA += __shfl_down(pA, off, 64);
            pB += __shfl_down(pB, off, 64);
        }
        if ((t & 63) == 0) { red[0][t >> 6] = pA; red[1][t >> 6] = pB; }
        __syncthreads();
        const float totA = ((red[0][0] + red[0][1]) + (red[0][2] + red[0][3]))
                         + ((red[0][4] + red[0][5]) + (red[0][6] + red[0][7]));
        const float totB = ((red[1][0] + red[1][1]) + (red[1][2] + red[1][3]))
                         + ((red[1][4] + red[1][5]) + (red[1][6] + red[1][7]));
        const float sclA = 19.59591794226543f / sqrtf(totA);   // sqrt(384)/nrm
        const float sclB = 19.59591794226543f / sqrtf(totB);

        if (t < DDIM) {
            const float2 ciA = __half22float2(csS[(r0 + rr) * DDIM + t]);
            const float2 ciB = __half22float2(csS[(r0 + rr + 1) * DDIM + t]);
            const float  GrA = fmaf(reA, ciA.x, imA * ciA.y);
            const float  GrB = fmaf(reB, ciB.x, imB * ciB.y);
            out[perm[r0 + rr] * DDIM + t]     = GrA * sclA;
            out[perm[r0 + rr + 1] * DDIM + t] = GrB * sclB;
        }
        __syncthreads();   // protect partl/red before next pass
    }
}

extern "C" void kernel_launch(void* const* d_in, const int* in_sizes, int n_in,
                              void* d_out, int out_size, void* d_ws, size_t ws_size,
                              hipStream_t stream)
{
    const float* pts = (const float*)d_in[0];
    const float* A   = (const float*)d_in[1];
    if (n_in >= 2 && in_sizes[0] == 3 * DDIM && in_sizes[1] == NPTS * 3) {
        pts = (const float*)d_in[1];
        A   = (const float*)d_in[0];
    }
    char* ws = (char*)d_ws;
    __half2* csS       = (__half2*)(ws + 0);
    float2*  xyS       = (float2*)(ws + 12582912);
    int*     perm      = (int*)(ws + 12648448);
    int*     cellStart = (int*)(ws + 12681216);
    float*   out       = (float*)d_out;

    setup_kernel<<<1, 1024, 0, stream>>>(pts, cellStart, perm, xyS);
    cs_kernel<<<NPTS / 8, DDIM, 0, stream>>>(pts, A, perm, csS);
    row_kernel<<<NBLK, NTHR, 0, stream>>>(csS, xyS, perm, cellStart, out);
}